// Round 5
// baseline (361.943 us; speedup 1.0000x reference)
//
#include <hip/hip_runtime.h>
#include <stdint.h>

// Problem constants
#define BATCH   2048
#define KBITS   14
#define MW      512    // packed mem row: 16384 bits = 512 words (2 KB)
#define BROW    128    // unified bit-row: h_in[0..63] | state[64..95] | s_out[96..127]
#define PAD     129    // LDS padded stride: bank=(lane+wd)&31 -> 2-way (free)

#define IM_F 33554432L   // 2048 * 16384 floats
#define SM_F 16777216L
#define OM_F 16777216L

// ---------------------------------------------------------------------------
// Swizzled in-lane pack format (tables + input bits):
//   wave chunk = 2048 entries; lane holds entries (j*64+lane)*4+{0..3}, j<8.
//   lane's u32 = sum_j nib[j] << 4j ; stored at word gw*64+lane (coalesced
//   256B/instr, ONE store per wave, no cross-lane ops).
// Lookup of entry E within a row (row = 512 words):
//   word = (E>>11)*64 + ((E>>2)&63),  bit = ((E>>8)&7)*4 + (E&3)
// (valid because row size 16384 and table bases are multiples of 2048).
__global__ __launch_bounds__(256) void pack_mem(const float4* __restrict__ im,
                                                const float4* __restrict__ sm,
                                                const float4* __restrict__ om,
                                                uint32_t* __restrict__ tbl) {
    const int gw = (blockIdx.x * 256 + threadIdx.x) >> 6;   // 0..32767
    const int lane = threadIdx.x & 63;
    const long f0 = (long)gw << 11;
    const float4* src;
    long eb;
    if (f0 < IM_F)              { src = im; eb = f0; }
    else if (f0 < IM_F + SM_F)  { src = sm; eb = f0 - IM_F; }
    else                        { src = om; eb = f0 - IM_F - SM_F; }
    const float4* p = src + (eb >> 2) + lane;
    float4 r[8];
#pragma unroll
    for (int j = 0; j < 8; j++) r[j] = p[j * 64];
    uint32_t w = 0;
#pragma unroll
    for (int j = 0; j < 8; j++) {
        uint32_t nib = (uint32_t)(r[j].x == 1.0f) | ((uint32_t)(r[j].y == 1.0f) << 1) |
                       ((uint32_t)(r[j].z == 1.0f) << 2) | ((uint32_t)(r[j].w == 1.0f) << 3);
        w |= nib << (4 * j);
    }
    tbl[(f0 >> 5) + lane] = w;
}

// Same swizzled format for input_bits (row = 4096 bits = 2 wave chunks).
__global__ __launch_bounds__(256) void pack_in(const int4* __restrict__ src,
                                               uint32_t* __restrict__ bits1) {
    const int gw = (blockIdx.x * 256 + threadIdx.x) >> 6;   // 0..4095
    const int lane = threadIdx.x & 63;
    const long f0 = (long)gw << 11;
    const int4* p = src + (f0 >> 2) + lane;
    int4 r[8];
#pragma unroll
    for (int j = 0; j < 8; j++) r[j] = p[j * 64];
    uint32_t w = 0;
#pragma unroll
    for (int j = 0; j < 8; j++) {
        uint32_t nib = (uint32_t)(r[j].x == 1) | ((uint32_t)(r[j].y == 1) << 1) |
                       ((uint32_t)(r[j].z == 1) << 2) | ((uint32_t)(r[j].w == 1) << 3);
        w |= nib << (4 * j);
    }
    bits1[(f0 >> 5) + lane] = w;
}

// state_bits -> ENTRY-ORDER bits in buf words 64..95 (shfl assembly; 8 MB,
// cheap). Wave = 2048 ints = 2 batch rows.
__global__ __launch_bounds__(256) void pack_st(const int4* __restrict__ src,
                                               uint32_t* __restrict__ buf) {
    const int gw = (blockIdx.x * 256 + threadIdx.x) >> 6;   // 0..1023
    const int lane = threadIdx.x & 63;
    const long ebase = (long)gw << 11;
    const int4* p = src + (ebase >> 2) + lane;
    int4 r[8];
#pragma unroll
    for (int j = 0; j < 8; j++) r[j] = p[j * 64];
    uint32_t w[8];
#pragma unroll
    for (int j = 0; j < 8; j++) {
        uint32_t nib = (uint32_t)(r[j].x == 1) | ((uint32_t)(r[j].y == 1) << 1) |
                       ((uint32_t)(r[j].z == 1) << 2) | ((uint32_t)(r[j].w == 1) << 3);
        uint32_t x = nib << (4 * (lane & 7));
        x |= __shfl_xor(x, 1, 64);
        x |= __shfl_xor(x, 2, 64);
        x |= __shfl_xor(x, 4, 64);
        w[j] = x;
    }
    if ((lane & 7) == 0) {
        const int s = lane >> 3;
        const long wbase = ebase >> 5;
#pragma unroll
        for (int j = 0; j < 8; j++) {
            long g = wbase + j * 8 + s;           // state word idx; 32 per row
            buf[(g >> 5) * BROW + 64 + (g & 31)] = w[j];
        }
    }
}

// ---------------------------------------------------------------------------
// RAM layer, lane = batch row; 64 rows staged in LDS (stride 129 -> 2-way
// free). Wave handles NW consecutive neurons (conn wave-uniform -> s_load);
// 14 LDS bit-extracts -> 14-bit address (k=0 MSB); one 4B gather in the
// neuron's 2KB swizzled row; ballot over batch; 64x64 bit transpose.
// MODE 0: src = bits1 (SWIZZLED rows), u16 store to buf words 0..63 (NW=16)
// MODE 1: src = buf (entry-order),     u8 store to buf words 96..127 (NW=8)
// MODE 2: src = buf (entry-order),     float4 output (NW=8; idx>=2048 -> +32)
template <int NW, int MODE>
__global__ __launch_bounds__(256) void ram_layer(const uint32_t* __restrict__ src,
                                                 const int* __restrict__ conn,
                                                 const uint32_t* __restrict__ memp,
                                                 uint32_t* __restrict__ dst,
                                                 float* __restrict__ fout) {
    __shared__ uint32_t lds[64 * PAD];
    const int tid = threadIdx.x;
    const int b0 = blockIdx.y * 64;
    {
        const uint4* g = (const uint4*)(src + (long)b0 * BROW);
        for (int v = tid; v < 64 * BROW / 4; v += 256) {
            uint4 d = g[v];
            int row = v >> 5;
            int col = (v & 31) * 4;
            uint32_t* p = lds + row * PAD + col;
            p[0] = d.x; p[1] = d.y; p[2] = d.z; p[3] = d.w;
        }
    }
    __syncthreads();

    const int lane = tid & 63;
    const int wv = __builtin_amdgcn_readfirstlane(tid >> 6);
    const int n0 = blockIdx.x * (4 * NW) + wv * NW;
    const uint32_t* myrow = lds + lane * PAD;

    unsigned long long msk = 0;
#pragma unroll 2
    for (int i = 0; i < NW; ++i) {
        const int n = n0 + i;
        const int* c = conn + n * KBITS;
        uint32_t addr = 0;
#pragma unroll
        for (int k = 0; k < KBITS; k++) {
            int idx = c[k];
            int wd, bit;
            if (MODE == 0) {               // swizzled source row
                wd = ((idx >> 11) << 6) | ((idx >> 2) & 63);
                bit = (((idx >> 8) & 7) << 2) | (idx & 3);
            } else {                       // entry-order source row
                wd = idx >> 5;
                if (MODE == 2 && idx >= 2048) wd += 32;   // s_out region
                bit = idx & 31;
            }
            addr = (addr << 1) | ((myrow[wd] >> bit) & 1u);
        }
        // swizzled table lookup
        uint32_t word = ((addr >> 11) << 6) | ((addr >> 2) & 63);
        uint32_t bit = (((addr >> 8) & 7) << 2) | (addr & 3);
        uint32_t v = memp[(long)n * MW + word];
        unsigned long long m = __ballot(((v >> bit) & 1u) != 0);
        msk = (lane == i) ? m : msk;
    }

    // 64x64 bit transpose across lanes.
    unsigned long long x = msk;
#define TSTEP(S, M)                                                         \
    {                                                                       \
        unsigned long long t =                                              \
            (unsigned long long)__shfl_xor((long long)x, S, 64);            \
        x = (lane & S) ? ((x & ~(M)) | ((t & ~(M)) >> S))                   \
                       : ((x & (M)) | ((t & (M)) << S));                    \
    }
    TSTEP(32, 0x00000000ffffffffULL)
    TSTEP(16, 0x0000ffff0000ffffULL)
    TSTEP(8,  0x00ff00ff00ff00ffULL)
    TSTEP(4,  0x0f0f0f0f0f0f0f0fULL)
    TSTEP(2,  0x3333333333333333ULL)
    TSTEP(1,  0x5555555555555555ULL)
#undef TSTEP

    // lane b holds bits for neurons n0..n0+NW-1 of batch row b0+b.
    if (MODE == 0) {
        ((uint16_t*)(dst + (long)(b0 + lane) * BROW))[n0 >> 4] = (uint16_t)x;
    } else if (MODE == 1) {
        ((uint8_t*)(dst + (long)(b0 + lane) * BROW + 96))[n0 >> 3] = (uint8_t)x;
    } else {
        float* o = fout + (long)(b0 + lane) * 1024 + n0;
        float4 f0, f1;
        f0.x = (float)((x >> 0) & 1); f0.y = (float)((x >> 1) & 1);
        f0.z = (float)((x >> 2) & 1); f0.w = (float)((x >> 3) & 1);
        f1.x = (float)((x >> 4) & 1); f1.y = (float)((x >> 5) & 1);
        f1.z = (float)((x >> 6) & 1); f1.w = (float)((x >> 7) & 1);
        ((float4*)o)[0] = f0;
        ((float4*)o)[1] = f1;
    }
}

// ---------------------------------------------------------------------------
extern "C" void kernel_launch(void* const* d_in, const int* in_sizes, int n_in,
                              void* d_out, int out_size, void* d_ws, size_t ws_size,
                              hipStream_t stream) {
    const int*   input_bits = (const int*)d_in[0];
    const int*   state_bits = (const int*)d_in[1];
    const int*   in_conn    = (const int*)d_in[2];
    const float* in_mem     = (const float*)d_in[3];
    const int*   st_conn    = (const int*)d_in[4];
    const float* st_mem     = (const float*)d_in[5];
    const int*   out_conn   = (const int*)d_in[6];
    const float* out_mem    = (const float*)d_in[7];
    float*       out        = (float*)d_out;

    // Workspace: bits1 [B][128] @0 (1MB, swizzled) | buf [B][128] @1MB (1MB,
    // entry-order) | tbl @2MB: im_p 4MB | sm_p 2MB | om_p 2MB (swizzled)
    char* ws = (char*)d_ws;
    uint32_t* bits1 = (uint32_t*)(ws);
    uint32_t* buf   = (uint32_t*)(ws + 1048576);
    uint32_t* tbl   = (uint32_t*)(ws + 2097152);
    uint32_t* im_p  = tbl;
    uint32_t* sm_p  = tbl + 1048576;
    uint32_t* om_p  = tbl + 1572864;

    pack_in <<<1024, 256, 0, stream>>>((const int4*)input_bits, bits1);
    pack_st <<<256,  256, 0, stream>>>((const int4*)state_bits, buf);
    pack_mem<<<8192, 256, 0, stream>>>((const float4*)in_mem, (const float4*)st_mem,
                                       (const float4*)out_mem, tbl);

    // Layer 1: bits1(swizzled) -> h_in (buf words 0..63)
    ram_layer<16, 0><<<dim3(32, 32), 256, 0, stream>>>(bits1, in_conn, im_p, buf, nullptr);
    // Layer 2: buf(h_in|state) -> s_out (buf words 96..127)
    ram_layer<8, 1><<<dim3(32, 32), 256, 0, stream>>>(buf, st_conn, sm_p, buf, nullptr);
    // Layer 3: buf(h_in|s_out) -> float output
    ram_layer<8, 2><<<dim3(32, 32), 256, 0, stream>>>(buf, out_conn, om_p, nullptr, out);
}

// Round 6
// 356.263 us; speedup vs baseline: 1.0159x; 1.0159x over previous
//
#include <hip/hip_runtime.h>
#include <stdint.h>

// Problem constants
#define BATCH   2048
#define KBITS   14
#define MW      512    // packed mem row: 16384 bits = 512 u32 words (2 KB)
#define BROW    128    // unified bit-row: h_in[0..63] | state[64..95] | s_out[96..127]
#define PAD     129    // LDS padded stride: bank=(lane+wd)&31 -> 2-way (free)

#define IM_F 33554432L   // 2048 * 16384 floats
#define SM_F 16777216L

// pack_all block ranges (each thread packs 8 entries -> 1 byte store)
#define BLK_MEM 32768   // 67,108,864 floats / 8 / 256
#define BLK_IN  4096    // 8,388,608 ints  / 8 / 256
#define BLK_ST  1024    // 2,097,152 ints  / 8 / 256

// ---------------------------------------------------------------------------
// Entry-order byte pack: thread t packs entries 8t..8t+7 into one byte stored
// at byte offset t (64B/wave coalesced stores, zero cross-lane ops, 2 loads
// per thread -> r2-style TLP-max structure, which measured fastest).
// Little-endian guarantees entry e sits at bit (e&31) of u32 word (e>>5).
__global__ __launch_bounds__(256) void pack_all(
    const float4* __restrict__ im, const float4* __restrict__ sm,
    const float4* __restrict__ om, const int4* __restrict__ inb,
    const int4* __restrict__ stb,
    uint8_t* __restrict__ tbl_b, uint8_t* __restrict__ bits1_b,
    uint8_t* __restrict__ buf_b) {
    const int blk = blockIdx.x;
    if (blk < BLK_MEM) {                       // mem tables -> tbl (flat)
        const long t = (long)blk * 256 + threadIdx.x;   // byte index
        const long e0 = t << 3;
        const float4* src;
        long eb;
        if (e0 < IM_F)             { src = im; eb = e0; }
        else if (e0 < IM_F + SM_F) { src = sm; eb = e0 - IM_F; }
        else                       { src = om; eb = e0 - IM_F - SM_F; }
        const float4* p = src + (eb >> 2);
        float4 a = p[0], b = p[1];
        uint32_t w = (uint32_t)(a.x == 1.0f)        | ((uint32_t)(a.y == 1.0f) << 1) |
                     ((uint32_t)(a.z == 1.0f) << 2) | ((uint32_t)(a.w == 1.0f) << 3) |
                     ((uint32_t)(b.x == 1.0f) << 4) | ((uint32_t)(b.y == 1.0f) << 5) |
                     ((uint32_t)(b.z == 1.0f) << 6) | ((uint32_t)(b.w == 1.0f) << 7);
        tbl_b[t] = (uint8_t)w;
    } else if (blk < BLK_MEM + BLK_IN) {       // input_bits -> bits1 (flat)
        const long t = (long)(blk - BLK_MEM) * 256 + threadIdx.x;
        const int4* p = inb + (t << 1);
        int4 a = p[0], b = p[1];
        uint32_t w = (uint32_t)(a.x == 1)        | ((uint32_t)(a.y == 1) << 1) |
                     ((uint32_t)(a.z == 1) << 2) | ((uint32_t)(a.w == 1) << 3) |
                     ((uint32_t)(b.x == 1) << 4) | ((uint32_t)(b.y == 1) << 5) |
                     ((uint32_t)(b.z == 1) << 6) | ((uint32_t)(b.w == 1) << 7);
        bits1_b[t] = (uint8_t)w;
    } else {                                   // state_bits -> buf words 64..95
        const long t = (long)(blk - BLK_MEM - BLK_IN) * 256 + threadIdx.x;
        const int4* p = stb + (t << 1);
        int4 a = p[0], b = p[1];
        uint32_t w = (uint32_t)(a.x == 1)        | ((uint32_t)(a.y == 1) << 1) |
                     ((uint32_t)(a.z == 1) << 2) | ((uint32_t)(a.w == 1) << 3) |
                     ((uint32_t)(b.x == 1) << 4) | ((uint32_t)(b.y == 1) << 5) |
                     ((uint32_t)(b.z == 1) << 6) | ((uint32_t)(b.w == 1) << 7);
        const long row = t >> 7;               // 128 bytes of state per row
        const long col = t & 127;
        buf_b[row * 512 + 256 + col] = (uint8_t)w;
    }
}

// ---------------------------------------------------------------------------
// RAM layer, lane = batch row; 64 rows staged in LDS (stride 129 -> 2-way
// free). Wave handles NW consecutive neurons, conn wave-uniform (s_load).
// Three phases to maximize memory ILP: (A) all NW addresses from LDS bit-
// extracts (k=0 is MSB), (B) NW INDEPENDENT table gathers in flight,
// (C) NW ballots + 64x64 bit transpose.
// MODE 0: u16 store to buf words 0..63   (h_in,  NW=16)
// MODE 1: u8  store to buf words 96..127 (s_out, NW=8)
// MODE 2: float4 output direct           (out,   NW=8; idx>=2048 -> +32 words)
template <int NW, int MODE>
__global__ __launch_bounds__(256) void ram_layer(const uint32_t* __restrict__ src,
                                                 const int* __restrict__ conn,
                                                 const uint32_t* __restrict__ memp,
                                                 uint32_t* __restrict__ dst,
                                                 float* __restrict__ fout) {
    __shared__ uint32_t lds[64 * PAD];
    const int tid = threadIdx.x;
    const int b0 = blockIdx.y * 64;
    {
        const uint4* g = (const uint4*)(src + (long)b0 * BROW);
        for (int v = tid; v < 64 * BROW / 4; v += 256) {
            uint4 d = g[v];
            int row = v >> 5;
            int col = (v & 31) * 4;
            uint32_t* p = lds + row * PAD + col;
            p[0] = d.x; p[1] = d.y; p[2] = d.z; p[3] = d.w;
        }
    }
    __syncthreads();

    const int lane = tid & 63;
    const int wv = __builtin_amdgcn_readfirstlane(tid >> 6);
    const int n0 = blockIdx.x * (4 * NW) + wv * NW;
    const uint32_t* myrow = lds + lane * PAD;

    // Phase A: addresses
    uint32_t addr[NW];
#pragma unroll
    for (int i = 0; i < NW; ++i) {
        const int* c = conn + (n0 + i) * KBITS;
        uint32_t a = 0;
#pragma unroll
        for (int k = 0; k < KBITS; k++) {
            int idx = c[k];
            int wd = idx >> 5;
            if (MODE == 2 && idx >= 2048) wd += 32;   // o_inp: s_out region
            a = (a << 1) | ((myrow[wd] >> (idx & 31)) & 1u);
        }
        addr[i] = a;
    }
    // Phase B: independent gathers (NW loads in flight)
    uint32_t val[NW];
#pragma unroll
    for (int i = 0; i < NW; ++i)
        val[i] = memp[(long)(n0 + i) * MW + (addr[i] >> 5)];
    // Phase C: ballots + select
    unsigned long long msk = 0;
#pragma unroll
    for (int i = 0; i < NW; ++i) {
        unsigned long long m = __ballot(((val[i] >> (addr[i] & 31)) & 1u) != 0);
        msk = (lane == i) ? m : msk;
    }

    // 64x64 bit transpose across lanes.
    unsigned long long x = msk;
#define TSTEP(S, M)                                                         \
    {                                                                       \
        unsigned long long t =                                              \
            (unsigned long long)__shfl_xor((long long)x, S, 64);            \
        x = (lane & S) ? ((x & ~(M)) | ((t & ~(M)) >> S))                   \
                       : ((x & (M)) | ((t & (M)) << S));                    \
    }
    TSTEP(32, 0x00000000ffffffffULL)
    TSTEP(16, 0x0000ffff0000ffffULL)
    TSTEP(8,  0x00ff00ff00ff00ffULL)
    TSTEP(4,  0x0f0f0f0f0f0f0f0fULL)
    TSTEP(2,  0x3333333333333333ULL)
    TSTEP(1,  0x5555555555555555ULL)
#undef TSTEP

    // lane b holds bits for neurons n0..n0+NW-1 of batch row b0+b.
    if (MODE == 0) {
        ((uint16_t*)(dst + (long)(b0 + lane) * BROW))[n0 >> 4] = (uint16_t)x;
    } else if (MODE == 1) {
        ((uint8_t*)(dst + (long)(b0 + lane) * BROW + 96))[n0 >> 3] = (uint8_t)x;
    } else {
        float* o = fout + (long)(b0 + lane) * 1024 + n0;
        float4 f0, f1;
        f0.x = (float)((x >> 0) & 1); f0.y = (float)((x >> 1) & 1);
        f0.z = (float)((x >> 2) & 1); f0.w = (float)((x >> 3) & 1);
        f1.x = (float)((x >> 4) & 1); f1.y = (float)((x >> 5) & 1);
        f1.z = (float)((x >> 6) & 1); f1.w = (float)((x >> 7) & 1);
        ((float4*)o)[0] = f0;
        ((float4*)o)[1] = f1;
    }
}

// ---------------------------------------------------------------------------
extern "C" void kernel_launch(void* const* d_in, const int* in_sizes, int n_in,
                              void* d_out, int out_size, void* d_ws, size_t ws_size,
                              hipStream_t stream) {
    const int*   input_bits = (const int*)d_in[0];
    const int*   state_bits = (const int*)d_in[1];
    const int*   in_conn    = (const int*)d_in[2];
    const float* in_mem     = (const float*)d_in[3];
    const int*   st_conn    = (const int*)d_in[4];
    const float* st_mem     = (const float*)d_in[5];
    const int*   out_conn   = (const int*)d_in[6];
    const float* out_mem    = (const float*)d_in[7];
    float*       out        = (float*)d_out;

    // Workspace: bits1 [B][128] @0 (1MB) | buf [B][128] @1MB (1MB) |
    //            tbl @2MB: im_p 4MB | sm_p 2MB | om_p 2MB   (all entry-order)
    char* ws = (char*)d_ws;
    uint32_t* bits1 = (uint32_t*)(ws);
    uint32_t* buf   = (uint32_t*)(ws + 1048576);
    uint32_t* tbl   = (uint32_t*)(ws + 2097152);
    uint32_t* im_p  = tbl;
    uint32_t* sm_p  = tbl + 1048576;
    uint32_t* om_p  = tbl + 1572864;

    pack_all<<<BLK_MEM + BLK_IN + BLK_ST, 256, 0, stream>>>(
        (const float4*)in_mem, (const float4*)st_mem, (const float4*)out_mem,
        (const int4*)input_bits, (const int4*)state_bits,
        (uint8_t*)tbl, (uint8_t*)bits1, (uint8_t*)buf);

    // Layer 1: bits1 -> h_in (buf words 0..63)
    ram_layer<16, 0><<<dim3(32, 32), 256, 0, stream>>>(bits1, in_conn, im_p, buf, nullptr);
    // Layer 2: buf(h_in|state) -> s_out (buf words 96..127)
    ram_layer<8, 1><<<dim3(32, 32), 256, 0, stream>>>(buf, st_conn, sm_p, buf, nullptr);
    // Layer 3: buf(h_in|s_out) -> float output
    ram_layer<8, 2><<<dim3(32, 32), 256, 0, stream>>>(buf, out_conn, om_p, nullptr, out);
}